// Round 14
// baseline (881.820 us; speedup 1.0000x reference)
//
#include <hip/hip_runtime.h>

#define T_STEPS 1000
#define B_SZ 64
#define N_SZ 512
#define BN_TOT (B_SZ * N_SZ)             /* 32768  */
#define TBN   ((size_t)T_STEPS * BN_TOT) /* 32.768M */

typedef __attribute__((ext_vector_type(4))) float f32x4;
typedef __attribute__((ext_vector_type(8))) short bf16x8;
typedef __attribute__((ext_vector_type(4))) unsigned uint32x4;
typedef unsigned short ushort_t;

// ---------------------------------------------------------------------------
// GEMM1 (fp32 vector): C[M x 512] = A[M x 512] * W^T  (W row-major [512][512])
// NUMERICS CONTRACT: k-ascending single-accumulator fp32 FMA chain —
// bit-identical to np/jax BLAS microkernels (spikes depend on it).
// STRUCTURE CONTRACT (R6/R8): single-buffer LDS, staging fenced by barriers
// both sides (reg-staged dbuf spills). (R9): no address swizzle.
// (R10, kept): BK=16 -> 16.9 KB LDS, VALUBusy 75%, 385 us.
// ---------------------------------------------------------------------------
__global__ __launch_bounds__(256, 4)
void sgemm_abt(const float* __restrict__ A, const float* __restrict__ W,
               float* __restrict__ C)
{
    constexpr int K = 512;
    constexpr int BK = 16;
    constexpr int LDT = 128 + 4;
    __shared__ float As[BK][LDT];
    __shared__ float Bs[BK][LDT];

    const int tid = threadIdx.x;
    const int tx = tid & 15;
    const int ty = tid >> 4;
    const size_t m0 = (size_t)blockIdx.y * 128;
    const int n0 = blockIdx.x * 128;

    float acc[8][8];
#pragma unroll
    for (int i = 0; i < 8; ++i)
#pragma unroll
        for (int j = 0; j < 8; ++j) acc[i][j] = 0.0f;

    for (int k0 = 0; k0 < K; k0 += BK) {
#pragma unroll
        for (int p = 0; p < 2; ++p) {
            int i = tid + p * 256;       // 0..511
            int r = i >> 2;              // tile row 0..127
            int q = i & 3;               // k-quad 0..3
            float4 va = *(const float4*)(A + (m0 + r) * K + k0 + q * 4);
            As[q * 4 + 0][r] = va.x; As[q * 4 + 1][r] = va.y;
            As[q * 4 + 2][r] = va.z; As[q * 4 + 3][r] = va.w;
            float4 vb = *(const float4*)(W + (size_t)(n0 + r) * K + k0 + q * 4);
            Bs[q * 4 + 0][r] = vb.x; Bs[q * 4 + 1][r] = vb.y;
            Bs[q * 4 + 2][r] = vb.z; Bs[q * 4 + 3][r] = vb.w;
        }
        __syncthreads();
#pragma unroll
        for (int k = 0; k < BK; ++k) {
            float a[8], b[8];
            *(float4*)&a[0] = *(const float4*)&As[k][ty * 8];
            *(float4*)&a[4] = *(const float4*)&As[k][ty * 8 + 4];
            *(float4*)&b[0] = *(const float4*)&Bs[k][tx * 4];
            *(float4*)&b[4] = *(const float4*)&Bs[k][tx * 4 + 64];
#pragma unroll
            for (int i = 0; i < 8; ++i)
#pragma unroll
                for (int j = 0; j < 8; ++j)
                    acc[i][j] = fmaf(a[i], b[j], acc[i][j]);
        }
        __syncthreads();
    }

#pragma unroll
    for (int i = 0; i < 8; ++i) {
        float* cp = C + (m0 + ty * 8 + i) * 512 + n0 + tx * 4;
        *(float4*)cp        = make_float4(acc[i][0], acc[i][1], acc[i][2], acc[i][3]);
        *(float4*)(cp + 64) = make_float4(acc[i][4], acc[i][5], acc[i][6], acc[i][7]);
    }
}

// ---------------------------------------------------------------------------
// W2 -> 2-way bf16 split along k: Wc[n][k'] with k' in [0,512)=hi,
// [512,1024)=mid.  w ~= h + m, residual <= 2^-16 |w| (u err ~0.01 << 0.56).
// ---------------------------------------------------------------------------
__global__ __launch_bounds__(256)
void w2_split(const float* __restrict__ W2, ushort_t* __restrict__ Wc)
{
    int i = blockIdx.x * 256 + threadIdx.x;      // 0..262143
    int n = i >> 9, k = i & 511;
    float w = W2[i];
    unsigned wb = __float_as_uint(w);
    float h = __uint_as_float(wb & 0xFFFF0000u);
    float r1 = w - h;                             // exact
    unsigned r1b = __float_as_uint(r1);
    size_t base = (size_t)n * 1024 + k;
    Wc[base]       = (ushort_t)(wb >> 16);
    Wc[base + 512] = (ushort_t)(r1b >> 16);
}

// ---------------------------------------------------------------------------
// bit-octet -> bf16x8 with values {0.0, 1.0} (exact); bit j -> element j.
// ---------------------------------------------------------------------------
union bfcast { uint32x4 u; bf16x8 v; };
__device__ __forceinline__ bf16x8 mexp8v(unsigned bb)
{
    bfcast c;
    c.u.x = (bb & 1u)        * 0x3F80u | ((bb >> 1) & 1u) * 0x3F800000u;
    c.u.y = ((bb >> 2) & 1u) * 0x3F80u | ((bb >> 3) & 1u) * 0x3F800000u;
    c.u.z = ((bb >> 4) & 1u) * 0x3F80u | ((bb >> 5) & 1u) * 0x3F800000u;
    c.u.w = ((bb >> 6) & 1u) * 0x3F80u | ((bb >> 7) & 1u) * 0x3F800000u;
    return c.v;
}

// ---------------------------------------------------------------------------
// GEMM2 (bf16 MFMA): C[64000 x 512] fp32 = spikes @ Wc^T, K'=1024.
// R14: ZERO LDS, ZERO barriers. A expands from the spike bitmask (4 MB,
// L2-hot) straight into registers; B fragments are per-lane 16B loads from
// Wc (1 MB, L2-resident; ~1 GB aggregate L2 traffic ≈ 30 us at 34.5 TB/s).
// The R13 barrier+vmcnt skeleton was the remaining cost (~175 us vs 28 us
// MFMA floor). FMA sequence per acc element identical to R13 (t-ascending,
// same mfma order) -> decoded bit-identical. #pragma unroll 1 keeps live
// ranges bounded (R6/R8 spill lesson); launch_bounds(256,3) -> 12 waves/CU.
// mask32 word for A row m, col k: m*16 + (k>>5), bit (k&31).
// ---------------------------------------------------------------------------
__global__ __launch_bounds__(256, 3)
void gemm2_mfma(const unsigned* __restrict__ Msk, const ushort_t* __restrict__ Wc,
                float* __restrict__ C)
{
    const int tid = threadIdx.x;
    const int m0 = blockIdx.y * 128;
    const int n0 = blockIdx.x * 128;
    const int wid = tid >> 6;
    const int lane = tid & 63;
    const int wm = (wid >> 1) * 64;
    const int wn = (wid & 1) * 64;
    const int fr = lane & 15;
    const int fq = lane >> 4;
    const int qsh = fq * 8;

    f32x4 acc[4][4] = {};

    // per-lane row bases (32-bit offsets; bases live in SGPRs)
    const size_t mrow[4] = {
        (size_t)(m0 + wm +  0 + fr) * 16, (size_t)(m0 + wm + 16 + fr) * 16,
        (size_t)(m0 + wm + 32 + fr) * 16, (size_t)(m0 + wm + 48 + fr) * 16 };
    const size_t brow[4] = {
        (size_t)(n0 + wn +  0 + fr) * 1024, (size_t)(n0 + wn + 16 + fr) * 1024,
        (size_t)(n0 + wn + 32 + fr) * 1024, (size_t)(n0 + wn + 48 + fr) * 1024 };

#pragma unroll 1
    for (int t = 0; t < 32; ++t) {
        const int k0 = t * 32;           // B col (K'=1024)
        const int kk = k0 & 511;         // A col (spikes repeat every 512)
        const int mword = kk >> 5;

        unsigned mw[4];
        bf16x8 b[4];
#pragma unroll
        for (int m = 0; m < 4; ++m) mw[m] = Msk[mrow[m] + mword];
#pragma unroll
        for (int n = 0; n < 4; ++n)
            b[n] = *(const bf16x8*)(Wc + brow[n] + k0 + qsh);

        bf16x8 a[4];
#pragma unroll
        for (int m = 0; m < 4; ++m) a[m] = mexp8v((mw[m] >> qsh) & 0xFFu);

#pragma unroll
        for (int m = 0; m < 4; ++m)
#pragma unroll
            for (int n = 0; n < 4; ++n)
                acc[m][n] = __builtin_amdgcn_mfma_f32_16x16x32_bf16(
                    a[m], b[n], acc[m][n], 0, 0, 0);
    }

#pragma unroll
    for (int m = 0; m < 4; ++m) {
        const int row = m0 + wm + m * 16 + fq * 4;
#pragma unroll
        for (int n = 0; n < 4; ++n) {
            const int col = n0 + wn + n * 16 + fr;
#pragma unroll
            for (int j = 0; j < 4; ++j)
                C[(size_t)(row + j) * 512 + col] = acc[m][n][j];
        }
    }
}

// ---------------------------------------------------------------------------
// scan1: per-(b,n) LIF recurrence, 8-deep prefetch. Arithmetic per step
// unchanged (bit-exact). Emits spike BITMASK via __ballot:
// Msk[t*512 + (idx>>6)] bit l = spike of idx=(idx&~63)|l.
// ---------------------------------------------------------------------------
__global__ __launch_bounds__(128)
void lif_scan(const float* __restrict__ ff, const float* __restrict__ st0,
              const float* __restrict__ leak_v, const float* __restrict__ thresh,
              float* __restrict__ spikes, float* __restrict__ states,
              unsigned long long* __restrict__ Msk)
{
    const int idx = blockIdx.x * 128 + threadIdx.x;
    const int n = idx & (N_SZ - 1);
    const int b = idx >> 9;

    float v = st0[idx];
    float s = st0[BN_TOT + idx];
    const float lv = leak_v[n];
    const float th = thresh[n];

    const float* fp = ff + (size_t)b * T_STEPS * N_SZ + n;
    float* sp  = spikes + idx;
    float* stp = states + idx;
    const int wslot = idx >> 6;
    const bool wlead = ((threadIdx.x & 63) == 0);

    float f[8];
#pragma unroll
    for (int j = 0; j < 8; ++j) f[j] = fp[(size_t)j * N_SZ];

    for (int t = 0; t < T_STEPS; t += 8) {
        float g[8];
#pragma unroll
        for (int j = 0; j < 8; ++j) g[j] = 0.f;
        if (t + 8 < T_STEPS) {
            const float* q = fp + (size_t)(t + 8) * N_SZ;
#pragma unroll
            for (int j = 0; j < 8; ++j) g[j] = q[(size_t)j * N_SZ];
        }
#pragma unroll
        for (int j = 0; j < 8; ++j) {
            v = lv * v * (1.0f - s) + f[j];
            s = (v > th) ? 1.0f : 0.0f;
            size_t o  = (size_t)(t + j) * BN_TOT;
            size_t o2 = (size_t)(t + j) * (2 * BN_TOT);
            sp[o] = s;
            stp[o2] = v;
            stp[o2 + BN_TOT] = s;
            unsigned long long bm = __ballot(s != 0.0f);
            if (Msk && wlead)
                Msk[(size_t)(t + j) * 512 + wslot] = bm;
        }
#pragma unroll
        for (int j = 0; j < 8; ++j) f[j] = g[j];
    }
}

// ---------------------------------------------------------------------------
// scan2: u[t] = leak_i*u[t-1] + y[t], in place over dec ([t][b][n]);
// 8-deep prefetch.
// ---------------------------------------------------------------------------
__global__ __launch_bounds__(128)
void li_scan(float* __restrict__ dec, const float* __restrict__ u0,
             const float* __restrict__ leak_i)
{
    const int idx = blockIdx.x * 128 + threadIdx.x;
    const int n = idx & (N_SZ - 1);

    float u = u0[idx];
    const float li = leak_i[n];
    float* p = dec + idx;

    float y[8];
#pragma unroll
    for (int j = 0; j < 8; ++j) y[j] = p[(size_t)j * BN_TOT];

    for (int t = 0; t < T_STEPS; t += 8) {
        float g[8];
#pragma unroll
        for (int j = 0; j < 8; ++j) g[j] = 0.f;
        if (t + 8 < T_STEPS) {
            float* q = p + (size_t)(t + 8) * BN_TOT;
#pragma unroll
            for (int j = 0; j < 8; ++j) g[j] = q[(size_t)j * BN_TOT];
        }
#pragma unroll
        for (int j = 0; j < 8; ++j) {
            u = fmaf(li, u, y[j]);
            p[(size_t)(t + j) * BN_TOT] = u;
        }
#pragma unroll
        for (int j = 0; j < 8; ++j) y[j] = g[j];
    }
}

// ---------------------------------------------------------------------------
extern "C" void kernel_launch(void* const* d_in, const int* in_sizes, int n_in,
                              void* d_out, int out_size, void* d_ws, size_t ws_size,
                              hipStream_t stream)
{
    (void)in_sizes; (void)n_in; (void)out_size;

    const float* X     = (const float*)d_in[0];
    const float* st_sn = (const float*)d_in[1];
    const float* st_li = (const float*)d_in[2];
    const float* W1    = (const float*)d_in[3];
    const float* W2    = (const float*)d_in[4];
    const float* lv    = (const float*)d_in[5];
    const float* li    = (const float*)d_in[6];
    const float* th    = (const float*)d_in[7];

    float* spikes = (float*)d_out;                // [T][B][N]
    float* states = spikes + TBN;                 // [T][2][B][N]
    float* dec    = states + 2 * TBN;             // [T][B][N]

    // ws layout: Wc [512][1024] bf16 (1 MiB) + spike mask [1000][512] u64 (4 MiB)
    const size_t WS_NEED = (size_t)512 * 1024 * 2 + (size_t)1000 * 512 * 8;
    const bool use_mfma = (ws_size >= WS_NEED);
    ushort_t* Wc = (ushort_t*)d_ws;
    unsigned long long* Msk = (unsigned long long*)(Wc + (size_t)512 * 1024);

    const dim3 gemm_grid(4, 500), gemm_block(256);
    const dim3 scan_grid(BN_TOT / 128), scan_block(128);

    if (use_mfma)
        w2_split<<<dim3(1024), dim3(256), 0, stream>>>(W2, Wc);

    // 1) FF = X @ W1^T (exact fp32 sequential-FMA path) -> dec [b][t][n]
    sgemm_abt<<<gemm_grid, gemm_block, 0, stream>>>(X, W1, dec);

    // 2) (v,s) scan; spikes + states (+ spike bitmask into ws)
    lif_scan<<<scan_grid, scan_block, 0, stream>>>(dec, st_sn, lv, th,
                                                   spikes, states,
                                                   use_mfma ? Msk
                                                            : (unsigned long long*)0);

    // 3) Y = spikes @ W2^T -> dec [t][b][n]
    if (use_mfma)
        gemm2_mfma<<<gemm_grid, gemm_block, 0, stream>>>((const unsigned*)Msk,
                                                         Wc, dec);
    else
        sgemm_abt<<<gemm_grid, gemm_block, 0, stream>>>(spikes, W2, dec);

    // 4) u scan in place over dec
    li_scan<<<scan_grid, scan_block, 0, stream>>>(dec, st_li, li);
}

// Round 15
// 690.734 us; speedup vs baseline: 1.2766x; 1.2766x over previous
//
#include <hip/hip_runtime.h>

#define T_STEPS 1000
#define B_SZ 64
#define N_SZ 512
#define BN_TOT (B_SZ * N_SZ)             /* 32768  */
#define TBN   ((size_t)T_STEPS * BN_TOT) /* 32.768M */

typedef __attribute__((ext_vector_type(4))) float f32x4;
typedef __attribute__((ext_vector_type(8))) short bf16x8;
typedef unsigned short ushort_t;

// ---------------------------------------------------------------------------
// GEMM1 (fp32 vector): C[M x 512] = A[M x 512] * W^T  (W row-major [512][512])
// NUMERICS CONTRACT: k-ascending single-accumulator fp32 FMA chain —
// bit-identical to np/jax BLAS microkernels (spikes depend on it).
// STRUCTURE CONTRACT (R6/R8): single-buffer LDS, staging fenced by barriers
// both sides (reg-staged dbuf spills). (R9): no address swizzle.
// (R10, kept): BK=16 -> 16.9 KB LDS, VALUBusy 75%, 385 us.
// ---------------------------------------------------------------------------
__global__ __launch_bounds__(256, 4)
void sgemm_abt(const float* __restrict__ A, const float* __restrict__ W,
               float* __restrict__ C)
{
    constexpr int K = 512;
    constexpr int BK = 16;
    constexpr int LDT = 128 + 4;
    __shared__ float As[BK][LDT];
    __shared__ float Bs[BK][LDT];

    const int tid = threadIdx.x;
    const int tx = tid & 15;
    const int ty = tid >> 4;
    const size_t m0 = (size_t)blockIdx.y * 128;
    const int n0 = blockIdx.x * 128;

    float acc[8][8];
#pragma unroll
    for (int i = 0; i < 8; ++i)
#pragma unroll
        for (int j = 0; j < 8; ++j) acc[i][j] = 0.0f;

    for (int k0 = 0; k0 < K; k0 += BK) {
#pragma unroll
        for (int p = 0; p < 2; ++p) {
            int i = tid + p * 256;       // 0..511
            int r = i >> 2;              // tile row 0..127
            int q = i & 3;               // k-quad 0..3
            float4 va = *(const float4*)(A + (m0 + r) * K + k0 + q * 4);
            As[q * 4 + 0][r] = va.x; As[q * 4 + 1][r] = va.y;
            As[q * 4 + 2][r] = va.z; As[q * 4 + 3][r] = va.w;
            float4 vb = *(const float4*)(W + (size_t)(n0 + r) * K + k0 + q * 4);
            Bs[q * 4 + 0][r] = vb.x; Bs[q * 4 + 1][r] = vb.y;
            Bs[q * 4 + 2][r] = vb.z; Bs[q * 4 + 3][r] = vb.w;
        }
        __syncthreads();
#pragma unroll
        for (int k = 0; k < BK; ++k) {
            float a[8], b[8];
            *(float4*)&a[0] = *(const float4*)&As[k][ty * 8];
            *(float4*)&a[4] = *(const float4*)&As[k][ty * 8 + 4];
            *(float4*)&b[0] = *(const float4*)&Bs[k][tx * 4];
            *(float4*)&b[4] = *(const float4*)&Bs[k][tx * 4 + 64];
#pragma unroll
            for (int i = 0; i < 8; ++i)
#pragma unroll
                for (int j = 0; j < 8; ++j)
                    acc[i][j] = fmaf(a[i], b[j], acc[i][j]);
        }
        __syncthreads();
    }

#pragma unroll
    for (int i = 0; i < 8; ++i) {
        float* cp = C + (m0 + ty * 8 + i) * 512 + n0 + tx * 4;
        *(float4*)cp        = make_float4(acc[i][0], acc[i][1], acc[i][2], acc[i][3]);
        *(float4*)(cp + 64) = make_float4(acc[i][4], acc[i][5], acc[i][6], acc[i][7]);
    }
}

// ---------------------------------------------------------------------------
// W2 -> single bf16 plane, ROUND-TO-NEAREST-EVEN (err <= 2^-9|w|, unbiased).
// R15: decoded error budget is 4.5 bf16-ulps (0.56); 1-term rounding adds
// ~0.07 ulp in the 3.3e7-sample tail (y std ~7e-4, u amp x2.3) — halves
// gemm2's K, MFMA count and B staging vs the 2-term split.
// ---------------------------------------------------------------------------
__global__ __launch_bounds__(256)
void w2_split(const float* __restrict__ W2, ushort_t* __restrict__ Wc)
{
    int i = blockIdx.x * 256 + threadIdx.x;      // 0..262143
    unsigned wb = __float_as_uint(W2[i]);
    unsigned rne = wb + 0x7FFFu + ((wb >> 16) & 1u);   // round-to-nearest-even
    Wc[i] = (ushort_t)(rne >> 16);
}

// ---------------------------------------------------------------------------
// bit-octet -> 4x u32, each u32 = two bf16 lanes {0, 0x3F80} (exact 0.0/1.0)
// ---------------------------------------------------------------------------
__device__ __forceinline__ uint4 mexp8(unsigned bb)
{
    uint4 r;
    r.x = ((bb) & 1u) * 0x3F80u        | (((bb) >> 1) & 1u) * 0x3F800000u;
    r.y = (((bb) >> 2) & 1u) * 0x3F80u | (((bb) >> 3) & 1u) * 0x3F800000u;
    r.z = (((bb) >> 4) & 1u) * 0x3F80u | (((bb) >> 5) & 1u) * 0x3F800000u;
    r.w = (((bb) >> 6) & 1u) * 0x3F80u | (((bb) >> 7) & 1u) * 0x3F800000u;
    return r;
}

// ---------------------------------------------------------------------------
// GEMM2 (bf16 MFMA): C[64000 x 512] fp32 = spikes @ Wc^T, K'=512 (1-term W2).
// R13-validated skeleton (R14's zero-LDS variant regressed — uncoalesced
// per-lane B loads + unhidden L2 latency; LDS staging reverted).
// A from spike bitmask (L2-hot): 1 mask u32 per thread per tile, expand
// bits -> bf16 {0,1.0} (exact) into As; B via global_load_lds, dbuf.
// mask32 word for A row m, col k: m*16 + (k>>5), bit (k&31).
// ---------------------------------------------------------------------------
__global__ __launch_bounds__(256, 2)
void gemm2_mfma(const unsigned* __restrict__ Msk, const ushort_t* __restrict__ Wc,
                float* __restrict__ C)
{
    constexpr int NT = 512 / 32;         // 16
    __shared__ ushort_t As[2][128 * 32];
    __shared__ ushort_t Bs[2][128 * 32];

    const int tid = threadIdx.x;
    const int m0 = blockIdx.y * 128;
    const int n0 = blockIdx.x * 128;
    const int wid = tid >> 6;
    const int lane = tid & 63;
    const int wm = (wid >> 1) * 64;
    const int wn = (wid & 1) * 64;
    const int fr = lane & 15;
    const int fq = lane >> 4;

    f32x4 acc[4][4] = {};

    const int rA = tid >> 2;             // 0..63 rows per half-tile (B stage)
    const int cA = (tid & 3) * 8;        // bf16 col within 32 (B stage)
    const size_t mrow0 = (size_t)(m0 + (tid >> 2)) * 16;
    const size_t mrow1 = (size_t)(m0 + 64 + (tid >> 2)) * 16;
    const int qsh = (tid & 3) * 8;       // bit group within the u32

    unsigned mw0, mw1;

#define STAGE_B(buf, t)                                                      \
    {                                                                        \
        const int k0_ = (t) * 32;                                            \
        _Pragma("unroll")                                                    \
        for (int i = 0; i < 2; ++i) {                                        \
            __builtin_amdgcn_global_load_lds(                                \
                (const __attribute__((address_space(1))) unsigned int*)      \
                    (Wc + (size_t)(n0 + i * 64 + rA) * 512 + k0_ + cA),      \
                (__attribute__((address_space(3))) unsigned int*)            \
                    (Bs[buf] + i * 2048 + tid * 8),                          \
                16, 0, 0);                                                   \
        }                                                                    \
    }
#define MLOAD(t)                                                             \
    {                                                                        \
        const int mword = (t);           /* k0>>5 = t (K'=512, one pass) */  \
        mw0 = Msk[mrow0 + mword];                                            \
        mw1 = Msk[mrow1 + mword];                                            \
    }
#define MSTORE(buf)                                                          \
    {                                                                        \
        *(uint4*)(As[buf] + tid * 8)        = mexp8((mw0 >> qsh) & 0xFFu);   \
        *(uint4*)(As[buf] + 2048 + tid * 8) = mexp8((mw1 >> qsh) & 0xFFu);   \
    }

    MLOAD(0);
    STAGE_B(0, 0);
    MSTORE(0);
    asm volatile("s_waitcnt vmcnt(0)" ::: "memory");
    __syncthreads();

    int cur = 0;
    for (int t = 0; t < NT; ++t) {
        if (t + 1 < NT) {
            MLOAD(t + 1);                // in flight during MFMA
            STAGE_B(cur ^ 1, t + 1);
        }

        bf16x8 a[4], b[4];
#pragma unroll
        for (int m = 0; m < 4; ++m)
            a[m] = *(const bf16x8*)(As[cur] + (wm + m * 16 + fr) * 32 + fq * 8);
#pragma unroll
        for (int n = 0; n < 4; ++n)
            b[n] = *(const bf16x8*)(Bs[cur] + (wn + n * 16 + fr) * 32 + fq * 8);
#pragma unroll
        for (int m = 0; m < 4; ++m)
#pragma unroll
            for (int n = 0; n < 4; ++n)
                acc[m][n] = __builtin_amdgcn_mfma_f32_16x16x32_bf16(
                    a[m], b[n], acc[m][n], 0, 0, 0);

        if (t + 1 < NT)
            MSTORE(cur ^ 1);             // expand after MFMA (latency hidden)

        asm volatile("s_waitcnt vmcnt(0)" ::: "memory");
        __syncthreads();
        cur ^= 1;
    }
#undef STAGE_B
#undef MLOAD
#undef MSTORE

#pragma unroll
    for (int m = 0; m < 4; ++m) {
        const int row = m0 + wm + m * 16 + fq * 4;
#pragma unroll
        for (int n = 0; n < 4; ++n) {
            const int col = n0 + wn + n * 16 + fr;
#pragma unroll
            for (int j = 0; j < 4; ++j)
                C[(size_t)(row + j) * 512 + col] = acc[m][n][j];
        }
    }
}

// ---------------------------------------------------------------------------
// scan1: per-(b,n) LIF recurrence, 8-deep prefetch. Arithmetic per step
// unchanged (bit-exact). Emits spike BITMASK via __ballot:
// Msk[t*512 + (idx>>6)] bit l = spike of idx=(idx&~63)|l.
// ---------------------------------------------------------------------------
__global__ __launch_bounds__(128)
void lif_scan(const float* __restrict__ ff, const float* __restrict__ st0,
              const float* __restrict__ leak_v, const float* __restrict__ thresh,
              float* __restrict__ spikes, float* __restrict__ states,
              unsigned long long* __restrict__ Msk)
{
    const int idx = blockIdx.x * 128 + threadIdx.x;
    const int n = idx & (N_SZ - 1);
    const int b = idx >> 9;

    float v = st0[idx];
    float s = st0[BN_TOT + idx];
    const float lv = leak_v[n];
    const float th = thresh[n];

    const float* fp = ff + (size_t)b * T_STEPS * N_SZ + n;
    float* sp  = spikes + idx;
    float* stp = states + idx;
    const int wslot = idx >> 6;
    const bool wlead = ((threadIdx.x & 63) == 0);

    float f[8];
#pragma unroll
    for (int j = 0; j < 8; ++j) f[j] = fp[(size_t)j * N_SZ];

    for (int t = 0; t < T_STEPS; t += 8) {
        float g[8];
#pragma unroll
        for (int j = 0; j < 8; ++j) g[j] = 0.f;
        if (t + 8 < T_STEPS) {
            const float* q = fp + (size_t)(t + 8) * N_SZ;
#pragma unroll
            for (int j = 0; j < 8; ++j) g[j] = q[(size_t)j * N_SZ];
        }
#pragma unroll
        for (int j = 0; j < 8; ++j) {
            v = lv * v * (1.0f - s) + f[j];
            s = (v > th) ? 1.0f : 0.0f;
            size_t o  = (size_t)(t + j) * BN_TOT;
            size_t o2 = (size_t)(t + j) * (2 * BN_TOT);
            sp[o] = s;
            stp[o2] = v;
            stp[o2 + BN_TOT] = s;
            unsigned long long bm = __ballot(s != 0.0f);
            if (Msk && wlead)
                Msk[(size_t)(t + j) * 512 + wslot] = bm;
        }
#pragma unroll
        for (int j = 0; j < 8; ++j) f[j] = g[j];
    }
}

// ---------------------------------------------------------------------------
// scan2: u[t] = leak_i*u[t-1] + y[t], in place over dec ([t][b][n]);
// 8-deep prefetch.
// ---------------------------------------------------------------------------
__global__ __launch_bounds__(128)
void li_scan(float* __restrict__ dec, const float* __restrict__ u0,
             const float* __restrict__ leak_i)
{
    const int idx = blockIdx.x * 128 + threadIdx.x;
    const int n = idx & (N_SZ - 1);

    float u = u0[idx];
    const float li = leak_i[n];
    float* p = dec + idx;

    float y[8];
#pragma unroll
    for (int j = 0; j < 8; ++j) y[j] = p[(size_t)j * BN_TOT];

    for (int t = 0; t < T_STEPS; t += 8) {
        float g[8];
#pragma unroll
        for (int j = 0; j < 8; ++j) g[j] = 0.f;
        if (t + 8 < T_STEPS) {
            float* q = p + (size_t)(t + 8) * BN_TOT;
#pragma unroll
            for (int j = 0; j < 8; ++j) g[j] = q[(size_t)j * BN_TOT];
        }
#pragma unroll
        for (int j = 0; j < 8; ++j) {
            u = fmaf(li, u, y[j]);
            p[(size_t)(t + j) * BN_TOT] = u;
        }
#pragma unroll
        for (int j = 0; j < 8; ++j) y[j] = g[j];
    }
}

// ---------------------------------------------------------------------------
extern "C" void kernel_launch(void* const* d_in, const int* in_sizes, int n_in,
                              void* d_out, int out_size, void* d_ws, size_t ws_size,
                              hipStream_t stream)
{
    (void)in_sizes; (void)n_in; (void)out_size;

    const float* X     = (const float*)d_in[0];
    const float* st_sn = (const float*)d_in[1];
    const float* st_li = (const float*)d_in[2];
    const float* W1    = (const float*)d_in[3];
    const float* W2    = (const float*)d_in[4];
    const float* lv    = (const float*)d_in[5];
    const float* li    = (const float*)d_in[6];
    const float* th    = (const float*)d_in[7];

    float* spikes = (float*)d_out;                // [T][B][N]
    float* states = spikes + TBN;                 // [T][2][B][N]
    float* dec    = states + 2 * TBN;             // [T][B][N]

    // ws layout: Wc [512][512] bf16 (0.5 MiB) + spike mask [1000][512] u64 (4 MiB)
    const size_t WS_NEED = (size_t)512 * 512 * 2 + (size_t)1000 * 512 * 8;
    const bool use_mfma = (ws_size >= WS_NEED);
    ushort_t* Wc = (ushort_t*)d_ws;
    unsigned long long* Msk = (unsigned long long*)(Wc + (size_t)512 * 512);

    const dim3 gemm_grid(4, 500), gemm_block(256);
    const dim3 scan_grid(BN_TOT / 128), scan_block(128);

    if (use_mfma)
        w2_split<<<dim3(1024), dim3(256), 0, stream>>>(W2, Wc);

    // 1) FF = X @ W1^T (exact fp32 sequential-FMA path) -> dec [b][t][n]
    sgemm_abt<<<gemm_grid, gemm_block, 0, stream>>>(X, W1, dec);

    // 2) (v,s) scan; spikes + states (+ spike bitmask into ws)
    lif_scan<<<scan_grid, scan_block, 0, stream>>>(dec, st_sn, lv, th,
                                                   spikes, states,
                                                   use_mfma ? Msk
                                                            : (unsigned long long*)0);

    // 3) Y = spikes @ W2^T -> dec [t][b][n]
    if (use_mfma)
        gemm2_mfma<<<gemm_grid, gemm_block, 0, stream>>>((const unsigned*)Msk,
                                                         Wc, dec);
    else
        sgemm_abt<<<gemm_grid, gemm_block, 0, stream>>>(spikes, W2, dec);

    // 4) u scan in place over dec
    li_scan<<<scan_grid, scan_block, 0, stream>>>(dec, st_li, li);
}